// Round 8
// baseline (80.983 us; speedup 1.0000x reference)
//
#include <hip/hip_runtime.h>
#include <stdint.h>

#define H_ 224
#define W_ 224
#define NPIX (H_ * W_)          // 50176
#define NQ4 (NPIX / 4)          // 12544 dwords per frame
#define ROWQ 56                 // dwords per row
#define NFRAMES 256
#define NT 1024
#define NW 16
#define CROWS 8
#define NCHUNK (H_ / CROWS)     // 28
#define CPX (CROWS * W_)        // 1792 floats per channel per chunk
#define CQ4 (CPX / 4)           // 448 gray dwords per chunk
#define STGF 5376               // floats per staging buffer (3 channels)

typedef __attribute__((address_space(1))) const uint32_t* gas_t;
typedef __attribute__((address_space(3))) uint32_t* las_t;

__device__ __forceinline__ void gload_lds16(const float* g, float* l) {
    __builtin_amdgcn_global_load_lds((gas_t)g, (las_t)l, 16, 0, 0);
}

__device__ __forceinline__ uint32_t udot4acc(uint32_t a, uint32_t b, uint32_t c) {
#if __has_builtin(__builtin_amdgcn_udot4)
    return __builtin_amdgcn_udot4(a, b, c, false);
#else
    c += (a & 0xffu) * (b & 0xffu);
    c += ((a >> 8) & 0xffu) * ((b >> 8) & 0xffu);
    c += ((a >> 16) & 0xffu) * ((b >> 16) & 0xffu);
    c += (a >> 24) * (b >> 24);
    return c;
#endif
}

__device__ __forceinline__ uint32_t quant1(float s) {
    float gr = s / 3.0f;
    float v = floorf(gr * 255.0f);
    v = fminf(fmaxf(v, 0.0f), 255.0f);
    return (uint32_t)(int)v;
}

// swizzled u8-packed histogram word index
__device__ __forceinline__ void hist_inc(uint32_t* hist, uint32_t a, uint32_t b) {
    uint32_t w = ((a << 6) | (b >> 2)) ^ (a & 31u);
    atomicAdd(&hist[w], 1u << ((b & 3u) << 3));
}

// ---- stats: con/dis/hom + sum(h^2) + cross sum(h_ij*h_ji), swizzle-decoded ----
__device__ __forceinline__ void stats_pass(const uint32_t* hist, int tid, int wave, int lane,
                                           double invnp, double inv2np2,
                                           double& conD, double& disD,
                                           double& homD, double& asmD) {
    uint32_t conU = 0, disU = 0, slinU = 0;
    float homF = 0.0f;
    #pragma unroll 4
    for (int itr = 0; itr < 16; ++itr) {
        int m = tid + (itr << 10);
        uint32_t w = hist[m];
        if (w) {                                   // empty rows skip (execz)
            int i = m >> 6;
            int b4 = (m & 63) ^ (i & 31);          // undo swizzle
            int d0 = i - (b4 << 2);
            slinU = udot4acc(w, w, slinU);
            #pragma unroll
            for (int k = 0; k < 4; ++k) {
                uint32_t bv = (w >> (k << 3)) & 0xffu;
                int d = d0 - k;
                uint32_t d2 = (uint32_t)(d * d);
                conU += bv * d2;
                disU += bv * (uint32_t)(d < 0 ? -d : d);
                homF += (float)bv * __builtin_amdgcn_rcpf(1.0f + (float)d2);
            }
        }
    }

    // cross term over 4x4 byte tiles; unit (it=lane, jt=(lane+s)&63)
    uint32_t scrU = 0;
    #pragma unroll
    for (int q = 0; q < 4; ++q) {
        int s = wave + (q << 4);
        int jt = (lane + s) & 63;
        uint32_t A[4], Bw[4];
        #pragma unroll
        for (int k = 0; k < 4; ++k) {
            int ia = 4 * lane + k;
            A[k]  = hist[((ia << 6) | jt)   ^ (ia & 31)];
            int ib = 4 * jt + k;
            Bw[k] = hist[((ib << 6) | lane) ^ (ib & 31)];
        }
        if ((A[0] | A[1] | A[2] | A[3]) && (Bw[0] | Bw[1] | Bw[2] | Bw[3])) {
            uint32_t x0 = __builtin_amdgcn_perm(Bw[1], Bw[0], 0x05010400u);
            uint32_t x1 = __builtin_amdgcn_perm(Bw[1], Bw[0], 0x07030602u);
            uint32_t x2 = __builtin_amdgcn_perm(Bw[3], Bw[2], 0x05010400u);
            uint32_t x3 = __builtin_amdgcn_perm(Bw[3], Bw[2], 0x07030602u);
            uint32_t t0 = __builtin_amdgcn_perm(x2, x0, 0x05040100u);
            uint32_t t1 = __builtin_amdgcn_perm(x2, x0, 0x07060302u);
            uint32_t t2 = __builtin_amdgcn_perm(x3, x1, 0x05040100u);
            uint32_t t3 = __builtin_amdgcn_perm(x3, x1, 0x07060302u);
            scrU = udot4acc(A[0], t0, scrU);
            scrU = udot4acc(A[1], t1, scrU);
            scrU = udot4acc(A[2], t2, scrU);
            scrU = udot4acc(A[3], t3, scrU);
        }
    }

    conD += (double)conU * invnp;
    disD += (double)disU * invnp;
    homD += (double)homF * invnp;
    asmD += ((double)slinU + (double)scrU) * inv2np2;
}

// ---------------- fused kernel: one frame per block ----------------
__global__ __launch_bounds__(NT, 4) void k_fused(const float* __restrict__ x,
                                                 uint32_t* __restrict__ gray,
                                                 float* __restrict__ out) {
    __shared__ uint32_t histA[16384];   // 64 KB u8 H[256][256]
    __shared__ uint32_t histB[16384];   // 64 KB; low 43008 B alias the DMA stage in pass A
    __shared__ double red[NW * 8];      // 1 KB

    const int f = blockIdx.x;
    const int bq = f >> 3, fq = f & 7;
    const int tid = threadIdx.x, lane = tid & 63, wave = tid >> 6;

    const float* xb = x + ((size_t)bq * 24 + fq) * NPIX;   // channel stride 8*NPIX
    uint32_t* gg = gray + (size_t)f * NQ4;
    float* stg = reinterpret_cast<float*>(histB);          // stage[2][STGF]

    // zero histA (histB is the stage for now)
    uint4* hA4 = reinterpret_cast<uint4*>(histA);
    uint4* hB4 = reinterpret_cast<uint4*>(histB);
    const uint4 z4 = make_uint4(0u, 0u, 0u, 0u);
    #pragma unroll
    for (int i = 0; i < 4; ++i) hA4[tid + (i << 10)] = z4;

    // DMA chunk 0 -> stage[0] (waves 9..15: 3 x 1KB instrs each = 21)
    if (wave >= 9) {
        int base = (wave - 9) * 3;
        #pragma unroll
        for (int k = 0; k < 3; ++k) {
            int idx = base + k;
            int ch = idx / 7, blk = idx % 7;
            gload_lds16(xb + (size_t)ch * (8 * NPIX) + blk * 256 + lane * 4,
                        stg + ch * CPX + blk * 256);
        }
    }
    __syncthreads();   // drains vmcnt(0): chunk 0 staged, histA zeroed

    // ---- pass A: stream; quant -> global gray + std + (0,1) atomics ----
    uint32_t s1 = 0, s2 = 0;
    for (int c = 0; c < NCHUNK; ++c) {
        const int bs = c & 1;
        if (c + 1 < NCHUNK && wave >= 9) {
            int base = (wave - 9) * 3;
            #pragma unroll
            for (int k = 0; k < 3; ++k) {
                int idx = base + k;
                int ch = idx / 7, blk = idx % 7;
                gload_lds16(xb + (size_t)ch * (8 * NPIX) + (size_t)(c + 1) * CPX + blk * 256 + lane * 4,
                            stg + (bs ^ 1) * STGF + ch * CPX + blk * 256);
            }
        }
        if (tid < CQ4) {                     // waves 0..6 process chunk c
            const float* st = stg + bs * STGF;
            float4 av = *reinterpret_cast<const float4*>(st + 0 * CPX + 4 * tid);
            float4 bv = *reinterpret_cast<const float4*>(st + 1 * CPX + 4 * tid);
            float4 cv = *reinterpret_cast<const float4*>(st + 2 * CPX + 4 * tid);
            uint32_t v0 = quant1(av.x + bv.x + cv.x);
            uint32_t v1 = quant1(av.y + bv.y + cv.y);
            uint32_t v2 = quant1(av.z + bv.z + cv.z);
            uint32_t v3 = quant1(av.w + bv.w + cv.w);
            uint32_t pk = v0 | (v1 << 8) | (v2 << 16) | (v3 << 24);
            gg[c * CQ4 + tid] = pk;          // gray write-back (L2-resident)
            s1 += v0 + v1 + v2 + v3;
            s2 += v0 * v0 + v1 * v1 + v2 * v2 + v3 * v3;
            // offset (0,1) pairs fused into the stream
            uint32_t nx = __shfl_down(pk, 1, 64);
            #pragma unroll
            for (int k = 0; k < 3; ++k) {    // in-dword pairs: always valid
                hist_inc(histA, (pk >> (8 * k)) & 0xffu, (pk >> (8 * k + 8)) & 0xffu);
            }
            int m56 = tid % 56;              // c*448 == 0 mod 56
            if (lane != 63 && m56 != 55) {   // cross-dword pair
                hist_inc(histA, pk >> 24, nx & 0xffu);
            }
        }
        __syncthreads();   // drains DMA(c+1); gray chunk visible
    }

    // deferred lane-63 cross-dword pairs for (0,1), read back from gray
    if (tid < 196) {
        int i = tid * 64 + 63;
        if (i % 56 != 55) {
            hist_inc(histA, gg[i] >> 24, gg[i + 1] & 0xffu);
        }
    }
    __syncthreads();

    double conD = 0.0, disD = 0.0, homD = 0.0, asmD = 0.0;
    const double npA = 49952.0, npB = 49729.0;
    const double invA = 1.0 / npA, invB = 1.0 / npB;
    const double invA2 = 1.0 / (2.0 * npA * npA), invB2 = 1.0 / (2.0 * npB * npB);

    stats_pass(histA, tid, wave, lane, invA, invA2, conD, disD, homD, asmD);   // (0,1)
    __syncthreads();

    // zero both histograms (stage is dead now)
    #pragma unroll
    for (int i = 0; i < 4; ++i) hA4[tid + (i << 10)] = z4;
    #pragma unroll
    for (int i = 0; i < 4; ++i) hB4[tid + (i << 10)] = z4;
    __syncthreads();

    // ---- pass B: (1,1) -> histA and (1,-1) -> histB in one sweep ----
    if (lane < 56) {
        for (int r = wave; r < H_ - 1; r += NW) {
            uint32_t A = gg[r * ROWQ + lane];
            uint32_t B = gg[(r + 1) * ROWQ + lane];
            uint32_t Bn = __shfl_down(B, 1, 64);
            uint32_t Bv1 = (B >> 8) | (Bn << 24);    // cols 4l+1 .. 4l+4
            uint32_t Bp = __shfl_up(B, 1, 64);
            uint32_t Bv2 = (B << 8) | (Bp >> 24);    // cols 4l-1 .. 4l+2
            int cb = lane * 4;
            #pragma unroll
            for (int k = 0; k < 4; ++k) {
                uint32_t a = (A >> (8 * k)) & 0xffu;
                if (cb + k < W_ - 1) hist_inc(histA, a, (Bv1 >> (8 * k)) & 0xffu);
                if (cb + k >= 1)     hist_inc(histB, a, (Bv2 >> (8 * k)) & 0xffu);
            }
        }
    }
    __syncthreads();

    stats_pass(histA, tid, wave, lane, invB, invB2, conD, disD, homD, asmD);   // (1,1)
    stats_pass(histB, tid, wave, lane, invB, invB2, conD, disD, homD, asmD);   // (1,-1)
    __syncthreads();

    // zero histA for pass C
    #pragma unroll
    for (int i = 0; i < 4; ++i) hA4[tid + (i << 10)] = z4;
    __syncthreads();

    // ---- pass C: (1,0) -> histA ----
    if (lane < 56) {
        for (int r = wave; r < H_ - 1; r += NW) {
            uint32_t A = gg[r * ROWQ + lane];
            uint32_t B = gg[(r + 1) * ROWQ + lane];
            #pragma unroll
            for (int k = 0; k < 4; ++k) {
                hist_inc(histA, (A >> (8 * k)) & 0xffu, (B >> (8 * k)) & 0xffu);
            }
        }
    }
    __syncthreads();

    stats_pass(histA, tid, wave, lane, invA, invA2, conD, disD, homD, asmD);   // (1,0)

    // ---- fused reduction of 6 doubles, finalize ----
    double vals[6] = {(double)s1, (double)s2, conD, disD, homD, asmD};
    #pragma unroll
    for (int off = 32; off; off >>= 1) {
        #pragma unroll
        for (int i = 0; i < 6; ++i) vals[i] += __shfl_down(vals[i], off, 64);
    }
    if (lane == 0) {
        #pragma unroll
        for (int i = 0; i < 6; ++i) red[wave * 8 + i] = vals[i];
    }
    __syncthreads();
    if (tid == 0) {
        double acc[6];
        #pragma unroll
        for (int i = 0; i < 6; ++i) {
            double t = red[i];
            for (int w = 1; w < NW; ++w) t += red[w * 8 + i];
            acc[i] = t;
        }
        double N = (double)NPIX;
        double mean = acc[0] / N;
        double var = acc[1] / N - mean * mean;
        if (var < 0.0) var = 0.0;
        float* op = out + f * 6;
        op[0] = (float)sqrt(var);
        op[1] = (float)(acc[2] * 0.25);
        op[2] = (float)(acc[3] * 0.25);
        op[3] = (float)(acc[4] * 0.25);
        op[4] = (float)(acc[5] * 0.25);
        op[5] = (float)sqrt(acc[5] * 0.25);
    }
}

extern "C" void kernel_launch(void* const* d_in, const int* in_sizes, int n_in,
                              void* d_out, int out_size, void* d_ws, size_t ws_size,
                              hipStream_t stream) {
    const float* x = (const float*)d_in[0];
    float* out = (float*)d_out;
    uint32_t* gray = (uint32_t*)d_ws;     // 12,845,056 bytes
    k_fused<<<NFRAMES, NT, 0, stream>>>(x, gray, out);
}